// Round 6
// baseline (9159.904 us; speedup 1.0000x reference)
//
#include <hip/hip_runtime.h>
#include <hip/hip_bf16.h>

typedef __hip_bfloat16 bf16;
typedef unsigned int uint_t;
typedef unsigned short ushort_t;
typedef _Float16 f16;
typedef f16 f16x8 __attribute__((ext_vector_type(8)));
typedef float f32x4 __attribute__((ext_vector_type(4)));

constexpr int NB  = 64;    // batch
constexpr int NL  = 64;    // words per sentence
constexpr int NT  = 63;    // template steps
constexpr int NCL = 16;    // chars per word
constexpr int NS  = 128;   // 1 + NL + NT
constexpr int ND  = 300;   // embed dim / hidden U
constexpr int NU  = 300;
constexpr int NCE = 8;
constexpr int NCF = 100;
constexpr int NCW = 5;
constexpr int NDIN = 400;  // ND + NCF
constexpr int NH4 = 1200;
constexpr int NH8 = 2400;
constexpr int NCLS = 3;
// LSTM scan kernel geometry
constexpr int BPG = 16;    // batches per block (one MFMA N-tile)
constexpr int NBG = 4;     // batch groups (64/16)
constexpr int KIT = 10;    // K iters of 32 (K=300 padded to 320)
constexpr int NJT = 19;    // unit tiles of 16 (300 padded to 304)
constexpr int HP  = 328;   // h^T LDS pitch in ushorts (bank-friendly, 16B-aligned rows)

__device__ __forceinline__ float sigf(float x)  { return 1.0f/(1.0f + __expf(-x)); }
__device__ __forceinline__ float tanhf_(float x){ return 2.0f/(1.0f + __expf(-2.0f*x)) - 1.0f; }
// fp16 (not bf16): all quantized tensors here are small-range; fp16 gives 8x lower
// rounding error at identical MFMA rate. fp32 accumulate everywhere.
__device__ __forceinline__ ushort_t f2h(float f){ f16 h = (f16)f; return *(ushort_t*)&h; }
__device__ __forceinline__ float h2f_(ushort_t u){ f16 h = *(f16*)&u; return (float)h; }
__device__ __forceinline__ uint_t pk2h(float a, float b){ return (uint_t)f2h(a) | ((uint_t)f2h(b) << 16); }

// ---------------- embedding + char CNN -> tree leaf rows ----------------
__global__ void k_embed(const int* __restrict__ x, const int* __restrict__ chars,
                        const float* __restrict__ wemb, const float* __restrict__ cemb,
                        const float* __restrict__ filt, float* __restrict__ tout)
{
    int bl = blockIdx.x;
    int b = bl / NL, l = bl - b*NL;
    __shared__ float e[NCL][NCE];
    __shared__ int wid;
    int tid = threadIdx.x;
    if (tid < NCL*NCE) {
        int ci = tid / NCE, cc = tid - (tid/NCE)*NCE;
        int ch = chars[bl*NCL + ci];
        e[ci][cc] = cemb[ch*NCE + cc];
    }
    if (tid == 0) wid = x[bl];
    __syncthreads();
    float* dst = tout + ((size_t)b*NS + 1 + l) * NDIN;
    if (tid < NCF) {
        float mx = -1e30f;
        for (int w = 0; w < NCL-NCW+1; ++w) {
            float acc = 0.f;
            #pragma unroll
            for (int k = 0; k < NCW; ++k)
                #pragma unroll
                for (int c = 0; c < NCE; ++c)
                    acc += e[w+k][c] * filt[(k*NCE+c)*NCF + tid];
            mx = fmaxf(mx, acc);
        }
        dst[ND + tid] = mx;
    }
    int w0 = wid;
    for (int i = tid; i < ND; i += blockDim.x)
        dst[i] = wemb[(size_t)w0*ND + i];
}

// ---------------- tree unfold ----------------
__global__ void k_tree(const int* __restrict__ temp, const int* __restrict__ len_,
                       float* __restrict__ tr)
{
    int half = blockIdx.x, b = blockIdx.y;
    int d0base = half*200;
    __shared__ float lds[65*200];
    int tid = threadIdx.x;
    float* base = tr + (size_t)b*NS*NDIN;
    for (int i = tid; i < 65*200; i += 256) {
        int r = i/200, d = i - r*200;
        lds[i] = base[r*NDIN + d0base + d];
    }
    __syncthreads();
    int ln = len_[b];
    for (int s = 1; s < NT; ++s) {
        int c0 = temp[(b*NT + s)*2 + 0];
        int c1 = temp[(b*NT + s)*2 + 1];
        int tgt = ln + 1 + s;
        if (tid < 200) {
            int d = tid;
            float p = 0.5f*(lds[c0*200 + d] + lds[c1*200 + d]);
            if (tgt <= NL) lds[tgt*200 + d] += p;
            else base[(size_t)tgt*NDIN + d0base + d] = p;
        }
    }
    __syncthreads();
    for (int i = tid; i < 65*200; i += 256) {
        int r = i/200, d = i - r*200;
        base[r*NDIN + d0base + d] = lds[i];
    }
}

// ---------------- generic fp32 transpose out[c][r] = in[r][c] ----------------
__global__ void k_transp(const float* __restrict__ in, float* __restrict__ out, int R, int C)
{
    __shared__ float tile[32][33];
    int c0 = blockIdx.x*32, r0 = blockIdx.y*32;
    for (int i = threadIdx.y; i < 32; i += 8) {
        int r = r0 + i, c = c0 + threadIdx.x;
        tile[i][threadIdx.x] = (r < R && c < C) ? in[(size_t)r*C + c] : 0.f;
    }
    __syncthreads();
    for (int i = threadIdx.y; i < 32; i += 8) {
        int c = c0 + i, r = r0 + threadIdx.x;
        if (c < C && r < R) out[(size_t)c*R + r] = tile[threadIdx.x][i];
    }
}

// ---------------- weight transpose + fp32->fp16, zero-padded ----------------
__global__ void k_wtb(const float* __restrict__ w, ushort_t* __restrict__ wt,
                      int K, int N, int Kpad, int Npad)
{
    __shared__ float tile[32][33];
    int k0 = blockIdx.x*32, n0 = blockIdx.y*32;
    for (int i = threadIdx.y; i < 32; i += 8) {
        int k = k0 + i, n = n0 + threadIdx.x;
        tile[i][threadIdx.x] = (k < K && n < N) ? w[(size_t)k*N + n] : 0.f;
    }
    __syncthreads();
    for (int i = threadIdx.y; i < 32; i += 8) {
        int n = n0 + i, k = k0 + threadIdx.x;
        if (n < Npad && k < Kpad) wt[(size_t)n*Kpad + k] = f2h(tile[threadIdx.x][i]);
    }
}

// ---------------- pack recurrent weights into MFMA A-fragment order (fp16) --------
__global__ void k_wpack(const float* __restrict__ wh, ushort_t* __restrict__ dst)
{
    int bx = blockIdx.x;            // bx = (j*4+g)*KIT + kit
    int kit = bx % KIT, jg = bx / KIT;
    int g = jg & 3, j = jg >> 2;
    int lane = threadIdx.x;
    int u = j*16 + (lane & 15);
    int k0 = kit*32 + (lane >> 4)*8;
    ushort_t v[8];
    #pragma unroll
    for (int jj = 0; jj < 8; ++jj) {
        int k = k0 + jj;
        float f = (u < NU && k < NU) ? wh[(size_t)k*NH4 + g*NU + u] : 0.f;
        v[jj] = f2h(f);
    }
    uint4 o;
    o.x = (uint_t)v[0] | ((uint_t)v[1] << 16);
    o.y = (uint_t)v[2] | ((uint_t)v[3] << 16);
    o.z = (uint_t)v[4] | ((uint_t)v[5] << 16);
    o.w = (uint_t)v[6] | ((uint_t)v[7] << 16);
    *(uint4*)&dst[((size_t)bx*64 + lane)*8] = o;
}

// ---------------- MFMA fp16 GEMM, 128x128 tile, BK=32 ----------------
template<int APERM, int AFMT, int OMODE, int ACT>
__global__ __launch_bounds__(256) void k_gemm_mfma(
    const void* __restrict__ Aa, const void* __restrict__ Ab2,
    const ushort_t* __restrict__ BT, const float* __restrict__ bias,
    void* __restrict__ Cv, int N, int Kpad, int ldc, int Ksrc)
{
    __shared__ __align__(16) ushort_t lds[2*512*8];
    int tid = threadIdx.x;
    int wave = tid >> 6, lane = tid & 63;
    int quad = lane >> 4, lr = lane & 15;
    int wm = wave >> 1, wn = wave & 1;
    int m0 = blockIdx.y * 128, n0 = blockIdx.x * 128;
    f32x4 acc[4][4] = {};
    const int nK = Kpad >> 5;
    for (int ks = 0; ks < nK; ++ks) {
        int k0 = ks << 5;
        #pragma unroll
        for (int i = 0; i < 2; ++i) {
            int c = tid + i*256;
            int mr = c >> 2, q = c & 3;
            int mg = m0 + mr;
            int arow = APERM ? ((mg & 63)*NS + (mg >> 6)) : mg;
            int kk = k0 + q*8;
            uint4 v;
            if (AFMT == 0) {
                v = *(const uint4*)&((const ushort_t*)Aa)[(size_t)arow*Kpad + kk];
            } else if (AFMT == 1) {
                if (kk < Ksrc) {
                    const float* src = (const float*)Aa + (size_t)arow*Ksrc + kk;
                    float4 v0 = *(const float4*)src;
                    float4 v1 = *(const float4*)(src + 4);
                    v.x = pk2h(v0.x, v0.y); v.y = pk2h(v0.z, v0.w);
                    v.z = pk2h(v1.x, v1.y); v.w = pk2h(v1.z, v1.w);
                } else { v.x = 0; v.y = 0; v.z = 0; v.w = 0; }
            } else {
                int sel = kk / 600, k2 = kk - sel*600;
                const float* hp = (const float*)Aa  + (size_t)arow*600 + k2;
                const float* ap = (const float*)Ab2 + (size_t)arow*600 + k2;
                float4 h0 = *(const float4*)hp, h1v = *(const float4*)(hp + 4);
                float4 a0 = *(const float4*)ap, a1v = *(const float4*)(ap + 4);
                float r0x,r0y,r0z,r0w,r1x,r1y,r1z,r1w;
                if (sel == 0)      { r0x=h0.x;r0y=h0.y;r0z=h0.z;r0w=h0.w; r1x=h1v.x;r1y=h1v.y;r1z=h1v.z;r1w=h1v.w; }
                else if (sel == 1) { r0x=a0.x;r0y=a0.y;r0z=a0.z;r0w=a0.w; r1x=a1v.x;r1y=a1v.y;r1z=a1v.z;r1w=a1v.w; }
                else if (sel == 2) { r0x=h0.x*a0.x;r0y=h0.y*a0.y;r0z=h0.z*a0.z;r0w=h0.w*a0.w;
                                     r1x=h1v.x*a1v.x;r1y=h1v.y*a1v.y;r1z=h1v.z*a1v.z;r1w=h1v.w*a1v.w; }
                else               { r0x=h0.x-a0.x;r0y=h0.y-a0.y;r0z=h0.z-a0.z;r0w=h0.w-a0.w;
                                     r1x=h1v.x-a1v.x;r1y=h1v.y-a1v.y;r1z=h1v.z-a1v.z;r1w=h1v.w-a1v.w; }
                v.x = pk2h(r0x, r0y); v.y = pk2h(r0z, r0w);
                v.z = pk2h(r1x, r1y); v.w = pk2h(r1z, r1w);
            }
            int mi = mr >> 4, r = mr & 15;
            int cd = (mi*4 + q)*16 + (r ^ (q*2));
            *(uint4*)&lds[cd*8] = v;
        }
        #pragma unroll
        for (int i = 0; i < 2; ++i) {
            int c = tid + i*256;
            int nr = c >> 2, q = c & 3;
            uint4 v = *(const uint4*)&BT[(size_t)(n0 + nr)*Kpad + k0 + q*8];
            int ni = nr >> 4, r = nr & 15;
            int cd = 512 + (ni*4 + q)*16 + (r ^ (q*2));
            *(uint4*)&lds[cd*8] = v;
        }
        __syncthreads();
        f16x8 afr[4], bfr[4];
        #pragma unroll
        for (int mi = 0; mi < 4; ++mi) {
            int mi8 = wm*4 + mi;
            int cd = (mi8*4 + quad)*16 + (lr ^ (quad*2));
            afr[mi] = *(const f16x8*)&lds[cd*8];
        }
        #pragma unroll
        for (int ni = 0; ni < 4; ++ni) {
            int ni8 = wn*4 + ni;
            int cd = 512 + (ni8*4 + quad)*16 + (lr ^ (quad*2));
            bfr[ni] = *(const f16x8*)&lds[cd*8];
        }
        #pragma unroll
        for (int mi = 0; mi < 4; ++mi)
            #pragma unroll
            for (int ni = 0; ni < 4; ++ni)
                acc[mi][ni] = __builtin_amdgcn_mfma_f32_16x16x32_f16(afr[mi], bfr[ni], acc[mi][ni], 0, 0, 0);
        __syncthreads();
    }
    #pragma unroll
    for (int mi = 0; mi < 4; ++mi) {
        int mbase = m0 + (wm*4 + mi)*16 + quad*4;
        #pragma unroll
        for (int ni = 0; ni < 4; ++ni) {
            int n = n0 + (wn*4 + ni)*16 + lr;
            if (OMODE == 0) {
                if (n < N) {
                    float bv = bias ? bias[n] : 0.f;
                    float* C = (float*)Cv;
                    #pragma unroll
                    for (int r2 = 0; r2 < 4; ++r2) {
                        float v = acc[mi][ni][r2] + bv;
                        if (ACT) v = fmaxf(v, 0.f);
                        C[(size_t)(mbase + r2)*ldc + n] = v;
                    }
                }
            } else if (OMODE == 1) {
                if (n < N) {
                    float bv = bias ? bias[n] : 0.f;
                    int t = mbase >> 6, b0 = mbase & 63;
                    uint2 o;
                    o.x = pk2h(acc[mi][ni][0] + bv, acc[mi][ni][1] + bv);
                    o.y = pk2h(acc[mi][ni][2] + bv, acc[mi][ni][3] + bv);
                    *(uint2*)&((ushort_t*)Cv)[((size_t)t*NH4 + n)*NB + b0] = o;
                }
            } else {
                if (n < ldc) {
                    float bv = (bias && n < N) ? bias[n] : 0.f;
                    ushort_t* C = (ushort_t*)Cv;
                    #pragma unroll
                    for (int r2 = 0; r2 < 4; ++r2) {
                        float v = acc[mi][ni][r2] + bv;
                        if (ACT) v = fmaxf(v, 0.f);
                        C[(size_t)(mbase + r2)*ldc + n] = (n < N) ? f2h(v) : (ushort_t)0;
                    }
                }
            }
        }
    }
}

// ---------------- generic tiled SIMT GEMM (attention) ----------------
template<int APERM, int OMODE, int ACT>
__global__ void k_gemm_nn(const float* __restrict__ A, const float* __restrict__ Bm,
                          const float* __restrict__ bias, void* __restrict__ Cv,
                          int M, int N, int K,
                          long long strideA, long long strideB, long long strideC)
{
    int bz = blockIdx.z;
    const float* Ab = A + (size_t)bz*strideA;
    const float* Bb = Bm + (size_t)bz*strideB;
    __shared__ float As[16][64];
    __shared__ float Bs[16][68];
    int n0 = blockIdx.x*64, m0 = blockIdx.y*64;
    int tid = threadIdx.x;
    int tm = tid/16, tn = tid - tm*16;
    float acc[4][4] = {};
    for (int k0 = 0; k0 < K; k0 += 16) {
        {
            int row = tid>>2, kq = tid&3;
            int m = m0 + row;
            int arow;
            if (APERM) { int tq = m>>6, bb = m&63; arow = bb*NS + tq; } else arow = m;
            const float* src = Ab + (size_t)arow*K + k0 + kq*4;
            float4 v;
            if (k0 + 16 <= K) v = *(const float4*)src;
            else {
                v.x = (k0+kq*4+0 < K)? src[0] : 0.f;
                v.y = (k0+kq*4+1 < K)? src[1] : 0.f;
                v.z = (k0+kq*4+2 < K)? src[2] : 0.f;
                v.w = (k0+kq*4+3 < K)? src[3] : 0.f;
            }
            As[kq*4+0][row]=v.x; As[kq*4+1][row]=v.y; As[kq*4+2][row]=v.z; As[kq*4+3][row]=v.w;
        }
        {
            int kk = tid>>4, nq = tid&15;
            int n = n0 + nq*4; int kg = k0 + kk;
            float4 v = {0,0,0,0};
            if (kg < K) {
                const float* src = Bb + (size_t)kg*N + n;
                if (n + 4 <= N) v = *(const float4*)src;
                else { if(n+0<N)v.x=src[0]; if(n+1<N)v.y=src[1]; if(n+2<N)v.z=src[2]; }
            }
            Bs[kk][nq*4+0]=v.x; Bs[kk][nq*4+1]=v.y; Bs[kk][nq*4+2]=v.z; Bs[kk][nq*4+3]=v.w;
        }
        __syncthreads();
        #pragma unroll
        for (int kk = 0; kk < 16; ++kk) {
            float4 a  = *(const float4*)&As[kk][tm*4];
            float4 bq = *(const float4*)&Bs[kk][tn*4];
            acc[0][0]+=a.x*bq.x; acc[0][1]+=a.x*bq.y; acc[0][2]+=a.x*bq.z; acc[0][3]+=a.x*bq.w;
            acc[1][0]+=a.y*bq.x; acc[1][1]+=a.y*bq.y; acc[1][2]+=a.y*bq.z; acc[1][3]+=a.y*bq.w;
            acc[2][0]+=a.z*bq.x; acc[2][1]+=a.z*bq.y; acc[2][2]+=a.z*bq.z; acc[2][3]+=a.z*bq.w;
            acc[3][0]+=a.w*bq.x; acc[3][1]+=a.w*bq.y; acc[3][2]+=a.w*bq.z; acc[3][3]+=a.w*bq.w;
        }
        __syncthreads();
    }
    #pragma unroll
    for (int i = 0; i < 4; ++i) {
        int m = m0 + tm*4 + i;
        #pragma unroll
        for (int j = 0; j < 4; ++j) {
            int n = n0 + tn*4 + j;
            if (n >= N) continue;
            float val = acc[i][j];
            if (bias) val += bias[n];
            if (ACT == 1) val = fmaxf(val, 0.f);
            float* C = (float*)Cv + (size_t)bz*strideC;
            C[(size_t)m*N + n] = val;
        }
    }
}

// ---------------- batched sim = h1 @ h2^T ----------------
__global__ void k_gemm_nt_sim(const float* __restrict__ h1g, const float* __restrict__ h2g,
                              float* __restrict__ sim, float* __restrict__ simT)
{
    int bz = blockIdx.z;
    const float* Ab = h1g + (size_t)bz*NS*(2*NU);
    const float* Bb = h2g + (size_t)bz*NS*(2*NU);
    __shared__ float As[16][64];
    __shared__ float Bs[16][68];
    int n0 = blockIdx.x*64, m0 = blockIdx.y*64;
    int tid = threadIdx.x;
    int tm = tid/16, tn = tid - tm*16;
    float acc[4][4] = {};
    const int K = 2*NU;
    for (int k0 = 0; k0 < K; k0 += 16) {
        int row = tid>>2, kq = tid&3;
        bool full = (k0 + 16 <= K);
        {
            const float* src = Ab + (size_t)(m0+row)*K + k0 + kq*4;
            float4 v = {0,0,0,0};
            if (full) v = *(const float4*)src;
            else { if(k0+kq*4+0<K)v.x=src[0]; if(k0+kq*4+1<K)v.y=src[1];
                   if(k0+kq*4+2<K)v.z=src[2]; if(k0+kq*4+3<K)v.w=src[3]; }
            As[kq*4+0][row]=v.x; As[kq*4+1][row]=v.y; As[kq*4+2][row]=v.z; As[kq*4+3][row]=v.w;
        }
        {
            const float* src = Bb + (size_t)(n0+row)*K + k0 + kq*4;
            float4 v = {0,0,0,0};
            if (full) v = *(const float4*)src;
            else { if(k0+kq*4+0<K)v.x=src[0]; if(k0+kq*4+1<K)v.y=src[1];
                   if(k0+kq*4+2<K)v.z=src[2]; if(k0+kq*4+3<K)v.w=src[3]; }
            Bs[kq*4+0][row]=v.x; Bs[kq*4+1][row]=v.y; Bs[kq*4+2][row]=v.z; Bs[kq*4+3][row]=v.w;
        }
        __syncthreads();
        #pragma unroll
        for (int kk = 0; kk < 16; ++kk) {
            float4 a  = *(const float4*)&As[kk][tm*4];
            float4 bq = *(const float4*)&Bs[kk][tn*4];
            acc[0][0]+=a.x*bq.x; acc[0][1]+=a.x*bq.y; acc[0][2]+=a.x*bq.z; acc[0][3]+=a.x*bq.w;
            acc[1][0]+=a.y*bq.x; acc[1][1]+=a.y*bq.y; acc[1][2]+=a.y*bq.z; acc[1][3]+=a.y*bq.w;
            acc[2][0]+=a.z*bq.x; acc[2][1]+=a.z*bq.y; acc[2][2]+=a.z*bq.z; acc[2][3]+=a.z*bq.w;
            acc[3][0]+=a.w*bq.x; acc[3][1]+=a.w*bq.y; acc[3][2]+=a.w*bq.z; acc[3][3]+=a.w*bq.w;
        }
        __syncthreads();
    }
    #pragma unroll
    for (int i = 0; i < 4; ++i) {
        int m = m0 + tm*4 + i;
        #pragma unroll
        for (int j = 0; j < 4; ++j) {
            int n = n0 + tn*4 + j;
            float val = acc[i][j];
            sim [((size_t)bz*NS + m)*NS + n] = val;
            simT[((size_t)bz*NS + n)*NS + m] = val;
        }
    }
}

// ---------------- row softmax (rows of length NS=128) ----------------
__global__ void k_softmax(const float* __restrict__ in, float* __restrict__ out)
{
    int r = blockIdx.x, tid = threadIdx.x;
    float v = in[(size_t)r*NS + tid];
    float m = v;
    for (int o = 32; o > 0; o >>= 1) m = fmaxf(m, __shfl_down(m, o, 64));
    __shared__ float red[2];
    if ((tid & 63) == 0) red[tid>>6] = m;
    __syncthreads();
    m = fmaxf(red[0], red[1]);
    float e = __expf(v - m);
    float s = e;
    for (int o = 32; o > 0; o >>= 1) s += __shfl_down(s, o, 64);
    __shared__ float red2[2];
    if ((tid & 63) == 0) red2[tid>>6] = s;
    __syncthreads();
    s = red2[0] + red2[1];
    out[(size_t)r*NS + tid] = e / s;
}

// ---------------- full bidirectional LSTM scan: ONE launch per phase ----------------
// grid (4 scans, 4 batch-groups) = 16 blocks, 512 threads (8 waves).
// Block owns ALL 300 units x 16 batches of one scan -> recurrence is block-local.
// Weights (fp16, fragment-packed) stream from per-XCD L2 each step; gates stay in
// registers; LDS holds only h^T fp16 [16][HP].
__global__ __launch_bounds__(512) void k_lstm_scan(
    const ushort_t* __restrict__ pre0, const ushort_t* __restrict__ pre1,
    const ushort_t* __restrict__ pre2, const ushort_t* __restrict__ pre3,
    const ushort_t* __restrict__ wpF, const ushort_t* __restrict__ wpB,
    float* __restrict__ hT1, float* __restrict__ hT2)
{
    __shared__ __align__(16) ushort_t hl[BPG*HP];
    int scan = blockIdx.x, bg = blockIdx.y;
    int tid = threadIdx.x, wave = tid >> 6, lane = tid & 63;
    int quad = lane >> 4, lr = lane & 15;
    const ushort_t* pre = (scan==0)?pre0:(scan==1)?pre1:(scan==2)?pre2:pre3;
    const ushort_t* wp = (scan & 1) ? wpB : wpF;
    float* hT = (scan < 2) ? hT1 : hT2;
    int coff = (scan & 1) ? NU : 0;
    int bglob = bg*BPG + lr;
    for (int i = tid; i < BPG*HP; i += 512) hl[i] = 0;
    __syncthreads();
    float creg[3][4] = {};
    for (int t = 0; t < NS; ++t) {
        int tt = (scan & 1) ? (NS-1-t) : t;
        const ushort_t* pp = pre + (size_t)tt*NH4*NB;
        f16x8 bfr[KIT];
        if (t > 0) {
            #pragma unroll
            for (int kit = 0; kit < KIT; ++kit)
                bfr[kit] = *(const f16x8*)&hl[lr*HP + kit*32 + quad*8];
        }
        __syncthreads();   // all B-frags read before hl is overwritten below
        #pragma unroll
        for (int ji = 0; ji < 3; ++ji) {
            int j = wave + ji*8;
            if (j < NJT) {
                f32x4 acc[4] = {};
                if (t > 0) {
                    #pragma unroll
                    for (int g = 0; g < 4; ++g) {
                        const ushort_t* wrow = wp + ((size_t)(j*4 + g)*KIT*64 + lane)*8;
                        #pragma unroll
                        for (int kit = 0; kit < KIT; ++kit) {
                            f16x8 af = *(const f16x8*)(wrow + (size_t)kit*64*8);
                            acc[g] = __builtin_amdgcn_mfma_f32_16x16x32_f16(af, bfr[kit], acc[g], 0, 0, 0);
                        }
                    }
                }
                ushort_t hb[4];
                #pragma unroll
                for (int r = 0; r < 4; ++r) {
                    int u = j*16 + quad*4 + r;
                    if (u < NU) {
                        float iv = acc[0][r] + h2f_(pp[(0*NU+u)*NB + bglob]);
                        float gv = acc[1][r] + h2f_(pp[(1*NU+u)*NB + bglob]);
                        float fv = acc[2][r] + h2f_(pp[(2*NU+u)*NB + bglob]);
                        float ov = acc[3][r] + h2f_(pp[(3*NU+u)*NB + bglob]);
                        float c = sigf(fv + 1.0f)*creg[ji][r] + sigf(iv)*tanhf_(gv);
                        float h = sigf(ov)*tanhf_(c);
                        creg[ji][r] = c;
                        hb[r] = f2h(h);
                        hT[((size_t)tt*(2*NU) + coff + u)*NB + bglob] = h;
                    } else hb[r] = 0;
                }
                uint2 o;
                o.x = (uint_t)hb[0] | ((uint_t)hb[1] << 16);
                o.y = (uint_t)hb[2] | ((uint_t)hb[3] << 16);
                *(uint2*)&hl[lr*HP + j*16 + quad*4] = o;
            }
        }
        __syncthreads();   // hl(t) complete before next step's B-frag loads
    }
}

// ---------------- pool ----------------
__global__ void k_pool(const float* __restrict__ dT, float* __restrict__ v, int voff)
{
    int u = blockIdx.x*4 + (threadIdx.x >> 6);
    int b = threadIdx.x & 63;
    float s = 0.f, m = -1e30f;
    for (int t = 0; t < NS; ++t) {
        float x = dT[((size_t)t*(2*NU) + u)*NB + b];
        s += x; m = fmaxf(m, x);
    }
    v[(size_t)b*NH8 + voff + u]       = s;
    v[(size_t)b*NH8 + voff + 600 + u] = m;
}

// ---------------- final MLP ----------------
__global__ void k_final(const float* __restrict__ v, const float* __restrict__ W1,
                        const float* __restrict__ b1, const float* __restrict__ W2,
                        const float* __restrict__ b2, float* __restrict__ out)
{
    __shared__ float vl[NH8];
    __shared__ float yl[ND];
    int b = blockIdx.x, tid = threadIdx.x;
    for (int i = tid; i < NH8; i += 320) vl[i] = v[(size_t)b*NH8 + i];
    __syncthreads();
    if (tid < ND) {
        float acc = b1[tid];
        for (int k = 0; k < NH8; ++k) acc += vl[k]*W1[(size_t)k*ND + tid];
        yl[tid] = tanhf_(acc);
    }
    __syncthreads();
    if (tid < NCLS) {
        float acc = b2[tid];
        for (int u = 0; u < ND; ++u) acc += yl[u]*W2[u*NCLS + tid];
        out[b*NCLS + tid] = acc;
    }
}

extern "C" void kernel_launch(void* const* d_in, const int* in_sizes, int n_in,
                              void* d_out, int out_size, void* d_ws, size_t ws_size,
                              hipStream_t stream)
{
    const int*   x1     = (const int*)d_in[0];
    const int*   x2     = (const int*)d_in[1];
    const int*   char1  = (const int*)d_in[2];
    const int*   char2  = (const int*)d_in[3];
    const int*   temp1  = (const int*)d_in[6];
    const int*   temp2  = (const int*)d_in[7];
    const int*   len1   = (const int*)d_in[8];
    const int*   len2   = (const int*)d_in[9];
    const float* wemb   = (const float*)d_in[10];
    const float* cemb   = (const float*)d_in[11];
    const float* cfilt  = (const float*)d_in[12];
    const float* eWxf   = (const float*)d_in[13];
    const float* eWhf   = (const float*)d_in[14];
    const float* ebf    = (const float*)d_in[15];
    const float* eWxb   = (const float*)d_in[16];
    const float* eWhb   = (const float*)d_in[17];
    const float* ebb    = (const float*)d_in[18];
    const float* decW   = (const float*)d_in[19];
    const float* decb   = (const float*)d_in[20];
    const float* dWxf   = (const float*)d_in[21];
    const float* dWhf   = (const float*)d_in[22];
    const float* dbf    = (const float*)d_in[23];
    const float* dWxb   = (const float*)d_in[24];
    const float* dWhb   = (const float*)d_in[25];
    const float* dbb    = (const float*)d_in[26];
    const float* aW1    = (const float*)d_in[27];
    const float* ab1    = (const float*)d_in[28];
    const float* aW2    = (const float*)d_in[29];
    const float* ab2    = (const float*)d_in[30];
    float* outp = (float*)d_out;

    float* W = (float*)d_ws;
    size_t off = 0;
    auto alloc = [&](size_t n){ float* p = W + off; off += n; return p; };
    float* t1   = alloc((size_t)NB*NS*NDIN);
    float* t2   = alloc((size_t)NB*NS*NDIN);
    float* h1   = alloc((size_t)NB*NS*(2*NU));
    float* h2   = alloc((size_t)NB*NS*(2*NU));
    float* hT1  = alloc((size_t)NS*(2*NU)*NB);
    float* hT2  = alloc((size_t)NS*(2*NU)*NB);
    float* vbuf = alloc((size_t)NB*NH8);
    float* eWTfF = alloc((size_t)1280*416/2);
    float* eWTbF = alloc((size_t)1280*416/2);
    float* dWTfF = alloc((size_t)1280*320/2);
    float* dWTbF = alloc((size_t)1280*320/2);
    float* decWTF= alloc((size_t)384*2400/2);
    float* p1bfF = alloc((size_t)8192*320/2);
    float* p2bfF = alloc((size_t)8192*320/2);
    size_t wpsz = (size_t)NJT*4*KIT*64*8;        // ushorts
    float* wpEfF = alloc(wpsz/2);
    float* wpEbF = alloc(wpsz/2);
    float* wpDfF = alloc(wpsz/2);
    float* wpDbF = alloc(wpsz/2);
    float* preF  = alloc((size_t)4*NS*NH4*NB/2); // fp16: 4 x (NS*NH4*NB)
    ushort_t* eWTf  = (ushort_t*)eWTfF;
    ushort_t* eWTb  = (ushort_t*)eWTbF;
    ushort_t* dWTf  = (ushort_t*)dWTfF;
    ushort_t* dWTb  = (ushort_t*)dWTbF;
    ushort_t* decWT = (ushort_t*)decWTF;
    ushort_t* p1bf  = (ushort_t*)p1bfF;
    ushort_t* p2bf  = (ushort_t*)p2bfF;
    ushort_t* wpEf  = (ushort_t*)wpEfF;
    ushort_t* wpEb  = (ushort_t*)wpEbF;
    ushort_t* wpDf  = (ushort_t*)wpDfF;
    ushort_t* wpDb  = (ushort_t*)wpDbF;
    ushort_t* preb[4];
    for (int i = 0; i < 4; ++i) preb[i] = (ushort_t*)preF + (size_t)i*NS*NH4*NB;
    // fp32 aliases inside the (phase-idle) pre region:
    float* sim   = preF;
    float* simT  = preF + 1048576;
    float* P1    = preF + 2097152;
    float* P2    = preF + 3145728;
    float* beta  = preF + (size_t)NS*NH4*NB/2;
    float* alpha = preF + (size_t)2*NS*NH4*NB/2;

    // 1. zero tree buffers, fill leaves
    hipMemsetAsync(t1, 0, (size_t)2*NB*NS*NDIN*sizeof(float), stream);
    k_embed<<<NB*NL, 128, 0, stream>>>(x1, char1, wemb, cemb, cfilt, t1);
    k_embed<<<NB*NL, 128, 0, stream>>>(x2, char2, wemb, cemb, cfilt, t2);
    k_tree<<<dim3(2, NB), 256, 0, stream>>>(temp1, len1, t1);
    k_tree<<<dim3(2, NB), 256, 0, stream>>>(temp2, len2, t2);

    // 2. weight prep: fp16 W^T for MFMA GEMMs + fragment-packed recurrent weights
    k_wtb<<<dim3(13,40), dim3(32,8), 0, stream>>>(eWxf, eWTf, 400, 1200, 416, 1280);
    k_wtb<<<dim3(13,40), dim3(32,8), 0, stream>>>(eWxb, eWTb, 400, 1200, 416, 1280);
    k_wtb<<<dim3(10,40), dim3(32,8), 0, stream>>>(dWxf, dWTf, 300, 1200, 320, 1280);
    k_wtb<<<dim3(10,40), dim3(32,8), 0, stream>>>(dWxb, dWTb, 300, 1200, 320, 1280);
    k_wtb<<<dim3(75,12), dim3(32,8), 0, stream>>>(decW, decWT, 2400, 300, 2400, 384);
    k_wpack<<<NJT*4*KIT, 64, 0, stream>>>(eWhf, wpEf);
    k_wpack<<<NJT*4*KIT, 64, 0, stream>>>(eWhb, wpEb);
    k_wpack<<<NJT*4*KIT, 64, 0, stream>>>(dWhf, wpDf);
    k_wpack<<<NJT*4*KIT, 64, 0, stream>>>(dWhb, wpDb);

    // 3. encoder pre-activations (MFMA fp16, fp32 A converted in staging)
    k_gemm_mfma<1,1,1,0><<<dim3(10,64), 256, 0, stream>>>(t1, nullptr, eWTf, ebf, preb[0], 1200, 416, 0, 400);
    k_gemm_mfma<1,1,1,0><<<dim3(10,64), 256, 0, stream>>>(t1, nullptr, eWTb, ebb, preb[1], 1200, 416, 0, 400);
    k_gemm_mfma<1,1,1,0><<<dim3(10,64), 256, 0, stream>>>(t2, nullptr, eWTf, ebf, preb[2], 1200, 416, 0, 400);
    k_gemm_mfma<1,1,1,0><<<dim3(10,64), 256, 0, stream>>>(t2, nullptr, eWTb, ebb, preb[3], 1200, 416, 0, 400);

    // 4. encoder LSTM: ONE launch, 128 steps block-local
    k_lstm_scan<<<dim3(4, NBG), 512, 0, stream>>>(preb[0], preb[1], preb[2], preb[3],
                                                  wpEf, wpEb, hT1, hT2);
    k_transp<<<dim3(2,2400), dim3(32,8), 0, stream>>>(hT1, h1, NS*(2*NU), NB);
    k_transp<<<dim3(2,2400), dim3(32,8), 0, stream>>>(hT2, h2, NS*(2*NU), NB);

    // 5. attention (SIMT fp32)
    k_gemm_nt_sim<<<dim3(2,2,NB), 256, 0, stream>>>(h1, h2, sim, simT);
    k_softmax<<<NB*NS, 128, 0, stream>>>(sim,  P1);
    k_softmax<<<NB*NS, 128, 0, stream>>>(simT, P2);
    k_gemm_nn<0,0,0><<<dim3(10,2,NB), 256, 0, stream>>>(P1, h2, nullptr, beta,  NS, 2*NU, NS,
                                                        (long long)NS*NS, (long long)NS*2*NU, (long long)NS*2*NU);
    k_gemm_nn<0,0,0><<<dim3(10,2,NB), 256, 0, stream>>>(P2, h1, nullptr, alpha, NS, 2*NU, NS,
                                                        (long long)NS*NS, (long long)NS*2*NU, (long long)NS*2*NU);

    // 6. m projection (MFMA, fused [h,a,h*a,h-a] staging, fp16 out [8192][320])
    k_gemm_mfma<0,2,2,1><<<dim3(3,64), 256, 0, stream>>>(h1, beta,  decWT, decb, p1bf, 300, 2400, 320, 600);
    k_gemm_mfma<0,2,2,1><<<dim3(3,64), 256, 0, stream>>>(h2, alpha, decWT, decb, p2bf, 300, 2400, 320, 600);

    // 7. decoder pre-activations (MFMA, fp16 A)
    k_gemm_mfma<1,0,1,0><<<dim3(10,64), 256, 0, stream>>>(p1bf, nullptr, dWTf, dbf, preb[0], 1200, 320, 0, 320);
    k_gemm_mfma<1,0,1,0><<<dim3(10,64), 256, 0, stream>>>(p1bf, nullptr, dWTb, dbb, preb[1], 1200, 320, 0, 320);
    k_gemm_mfma<1,0,1,0><<<dim3(10,64), 256, 0, stream>>>(p2bf, nullptr, dWTf, dbf, preb[2], 1200, 320, 0, 320);
    k_gemm_mfma<1,0,1,0><<<dim3(10,64), 256, 0, stream>>>(p2bf, nullptr, dWTb, dbb, preb[3], 1200, 320, 0, 320);

    // 8. decoder LSTM: ONE launch
    k_lstm_scan<<<dim3(4, NBG), 512, 0, stream>>>(preb[0], preb[1], preb[2], preb[3],
                                                  wpDf, wpDb, hT1, hT2);

    // 9. pool + final MLP
    k_pool<<<150, 256, 0, stream>>>(hT1, vbuf, 0);
    k_pool<<<150, 256, 0, stream>>>(hT2, vbuf, 1200);
    k_final<<<NB, 320, 0, stream>>>(vbuf, aW1, ab1, aW2, ab2, outp);
}

// Round 7
// 2904.520 us; speedup vs baseline: 3.1537x; 3.1537x over previous
//
#include <hip/hip_runtime.h>
#include <hip/hip_bf16.h>

typedef __hip_bfloat16 bf16;
typedef unsigned int uint_t;
typedef unsigned short ushort_t;
typedef _Float16 f16;
typedef f16 f16x8 __attribute__((ext_vector_type(8)));
typedef float f32x4 __attribute__((ext_vector_type(4)));

constexpr int NB  = 64;    // batch
constexpr int NL  = 64;    // words per sentence
constexpr int NT  = 63;    // template steps
constexpr int NCL = 16;    // chars per word
constexpr int NS  = 128;   // 1 + NL + NT
constexpr int ND  = 300;   // embed dim / hidden U
constexpr int NU  = 300;
constexpr int NCE = 8;
constexpr int NCF = 100;
constexpr int NCW = 5;
constexpr int NDIN = 400;  // ND + NCF
constexpr int NH4 = 1200;
constexpr int NH8 = 2400;
constexpr int NCLS = 3;
// LSTM scan geometry: 19 j-tiles (16 units) x 4 scans = 76 persistent blocks
constexpr int KIT = 10;    // K iters of 32 (K=300 padded to 320)
constexpr int JT  = 19;    // unit tiles of 16 (300 padded to 304)
constexpr int HXP = 320;   // h^T exchange pitch in ushorts

__device__ __forceinline__ float sigf(float x)  { return 1.0f/(1.0f + __expf(-x)); }
__device__ __forceinline__ float tanhf_(float x){ return 2.0f/(1.0f + __expf(-2.0f*x)) - 1.0f; }
// fp16 (not bf16): all quantized tensors here are small-range; fp16 gives 8x lower
// rounding error at identical MFMA rate. fp32 accumulate everywhere.
__device__ __forceinline__ ushort_t f2h(float f){ f16 h = (f16)f; return *(ushort_t*)&h; }
__device__ __forceinline__ float h2f_(ushort_t u){ f16 h = *(f16*)&u; return (float)h; }
__device__ __forceinline__ uint_t pk2h(float a, float b){ return (uint_t)f2h(a) | ((uint_t)f2h(b) << 16); }

// ---------------- embedding + char CNN -> tree leaf rows ----------------
__global__ void k_embed(const int* __restrict__ x, const int* __restrict__ chars,
                        const float* __restrict__ wemb, const float* __restrict__ cemb,
                        const float* __restrict__ filt, float* __restrict__ tout)
{
    int bl = blockIdx.x;
    int b = bl / NL, l = bl - b*NL;
    __shared__ float e[NCL][NCE];
    __shared__ int wid;
    int tid = threadIdx.x;
    if (tid < NCL*NCE) {
        int ci = tid / NCE, cc = tid - (tid/NCE)*NCE;
        int ch = chars[bl*NCL + ci];
        e[ci][cc] = cemb[ch*NCE + cc];
    }
    if (tid == 0) wid = x[bl];
    __syncthreads();
    float* dst = tout + ((size_t)b*NS + 1 + l) * NDIN;
    if (tid < NCF) {
        float mx = -1e30f;
        for (int w = 0; w < NCL-NCW+1; ++w) {
            float acc = 0.f;
            #pragma unroll
            for (int k = 0; k < NCW; ++k)
                #pragma unroll
                for (int c = 0; c < NCE; ++c)
                    acc += e[w+k][c] * filt[(k*NCE+c)*NCF + tid];
            mx = fmaxf(mx, acc);
        }
        dst[ND + tid] = mx;
    }
    int w0 = wid;
    for (int i = tid; i < ND; i += blockDim.x)
        dst[i] = wemb[(size_t)w0*ND + i];
}

// ---------------- tree unfold ----------------
__global__ void k_tree(const int* __restrict__ temp, const int* __restrict__ len_,
                       float* __restrict__ tr)
{
    int half = blockIdx.x, b = blockIdx.y;
    int d0base = half*200;
    __shared__ float lds[65*200];
    int tid = threadIdx.x;
    float* base = tr + (size_t)b*NS*NDIN;
    for (int i = tid; i < 65*200; i += 256) {
        int r = i/200, d = i - r*200;
        lds[i] = base[r*NDIN + d0base + d];
    }
    __syncthreads();
    int ln = len_[b];
    for (int s = 1; s < NT; ++s) {
        int c0 = temp[(b*NT + s)*2 + 0];
        int c1 = temp[(b*NT + s)*2 + 1];
        int tgt = ln + 1 + s;
        if (tid < 200) {
            int d = tid;
            float p = 0.5f*(lds[c0*200 + d] + lds[c1*200 + d]);
            if (tgt <= NL) lds[tgt*200 + d] += p;
            else base[(size_t)tgt*NDIN + d0base + d] = p;
        }
    }
    __syncthreads();
    for (int i = tid; i < 65*200; i += 256) {
        int r = i/200, d = i - r*200;
        base[r*NDIN + d0base + d] = lds[i];
    }
}

// ---------------- generic fp32 transpose out[c][r] = in[r][c] ----------------
__global__ void k_transp(const float* __restrict__ in, float* __restrict__ out, int R, int C)
{
    __shared__ float tile[32][33];
    int c0 = blockIdx.x*32, r0 = blockIdx.y*32;
    for (int i = threadIdx.y; i < 32; i += 8) {
        int r = r0 + i, c = c0 + threadIdx.x;
        tile[i][threadIdx.x] = (r < R && c < C) ? in[(size_t)r*C + c] : 0.f;
    }
    __syncthreads();
    for (int i = threadIdx.y; i < 32; i += 8) {
        int c = c0 + i, r = r0 + threadIdx.x;
        if (c < C && r < R) out[(size_t)c*R + r] = tile[threadIdx.x][i];
    }
}

// ---------------- weight transpose + fp32->fp16, zero-padded ----------------
__global__ void k_wtb(const float* __restrict__ w, ushort_t* __restrict__ wt,
                      int K, int N, int Kpad, int Npad)
{
    __shared__ float tile[32][33];
    int k0 = blockIdx.x*32, n0 = blockIdx.y*32;
    for (int i = threadIdx.y; i < 32; i += 8) {
        int k = k0 + i, n = n0 + threadIdx.x;
        tile[i][threadIdx.x] = (k < K && n < N) ? w[(size_t)k*N + n] : 0.f;
    }
    __syncthreads();
    for (int i = threadIdx.y; i < 32; i += 8) {
        int n = n0 + i, k = k0 + threadIdx.x;
        if (n < Npad && k < Kpad) wt[(size_t)n*Kpad + k] = f2h(tile[threadIdx.x][i]);
    }
}

// ---------------- pack recurrent weights into MFMA A-fragment order (fp16) --------
__global__ void k_wpack(const float* __restrict__ wh, ushort_t* __restrict__ dst)
{
    int bx = blockIdx.x;            // bx = (j*4+g)*KIT + kit
    int kit = bx % KIT, jg = bx / KIT;
    int g = jg & 3, j = jg >> 2;
    int lane = threadIdx.x;
    int u = j*16 + (lane & 15);
    int k0 = kit*32 + (lane >> 4)*8;
    ushort_t v[8];
    #pragma unroll
    for (int jj = 0; jj < 8; ++jj) {
        int k = k0 + jj;
        float f = (u < NU && k < NU) ? wh[(size_t)k*NH4 + g*NU + u] : 0.f;
        v[jj] = f2h(f);
    }
    uint4 o;
    o.x = (uint_t)v[0] | ((uint_t)v[1] << 16);
    o.y = (uint_t)v[2] | ((uint_t)v[3] << 16);
    o.z = (uint_t)v[4] | ((uint_t)v[5] << 16);
    o.w = (uint_t)v[6] | ((uint_t)v[7] << 16);
    *(uint4*)&dst[((size_t)bx*64 + lane)*8] = o;
}

// ---------------- MFMA fp16 GEMM, 128x128 tile, BK=32 ----------------
template<int APERM, int AFMT, int OMODE, int ACT>
__global__ __launch_bounds__(256) void k_gemm_mfma(
    const void* __restrict__ Aa, const void* __restrict__ Ab2,
    const ushort_t* __restrict__ BT, const float* __restrict__ bias,
    void* __restrict__ Cv, int N, int Kpad, int ldc, int Ksrc)
{
    __shared__ __align__(16) ushort_t lds[2*512*8];
    int tid = threadIdx.x;
    int wave = tid >> 6, lane = tid & 63;
    int quad = lane >> 4, lr = lane & 15;
    int wm = wave >> 1, wn = wave & 1;
    int m0 = blockIdx.y * 128, n0 = blockIdx.x * 128;
    f32x4 acc[4][4] = {};
    const int nK = Kpad >> 5;
    for (int ks = 0; ks < nK; ++ks) {
        int k0 = ks << 5;
        #pragma unroll
        for (int i = 0; i < 2; ++i) {
            int c = tid + i*256;
            int mr = c >> 2, q = c & 3;
            int mg = m0 + mr;
            int arow = APERM ? ((mg & 63)*NS + (mg >> 6)) : mg;
            int kk = k0 + q*8;
            uint4 v;
            if (AFMT == 0) {
                v = *(const uint4*)&((const ushort_t*)Aa)[(size_t)arow*Kpad + kk];
            } else if (AFMT == 1) {
                if (kk < Ksrc) {
                    const float* src = (const float*)Aa + (size_t)arow*Ksrc + kk;
                    float4 v0 = *(const float4*)src;
                    float4 v1 = *(const float4*)(src + 4);
                    v.x = pk2h(v0.x, v0.y); v.y = pk2h(v0.z, v0.w);
                    v.z = pk2h(v1.x, v1.y); v.w = pk2h(v1.z, v1.w);
                } else { v.x = 0; v.y = 0; v.z = 0; v.w = 0; }
            } else {
                int sel = kk / 600, k2 = kk - sel*600;
                const float* hp = (const float*)Aa  + (size_t)arow*600 + k2;
                const float* ap = (const float*)Ab2 + (size_t)arow*600 + k2;
                float4 h0 = *(const float4*)hp, h1v = *(const float4*)(hp + 4);
                float4 a0 = *(const float4*)ap, a1v = *(const float4*)(ap + 4);
                float r0x,r0y,r0z,r0w,r1x,r1y,r1z,r1w;
                if (sel == 0)      { r0x=h0.x;r0y=h0.y;r0z=h0.z;r0w=h0.w; r1x=h1v.x;r1y=h1v.y;r1z=h1v.z;r1w=h1v.w; }
                else if (sel == 1) { r0x=a0.x;r0y=a0.y;r0z=a0.z;r0w=a0.w; r1x=a1v.x;r1y=a1v.y;r1z=a1v.z;r1w=a1v.w; }
                else if (sel == 2) { r0x=h0.x*a0.x;r0y=h0.y*a0.y;r0z=h0.z*a0.z;r0w=h0.w*a0.w;
                                     r1x=h1v.x*a1v.x;r1y=h1v.y*a1v.y;r1z=h1v.z*a1v.z;r1w=h1v.w*a1v.w; }
                else               { r0x=h0.x-a0.x;r0y=h0.y-a0.y;r0z=h0.z-a0.z;r0w=h0.w-a0.w;
                                     r1x=h1v.x-a1v.x;r1y=h1v.y-a1v.y;r1z=h1v.z-a1v.z;r1w=h1v.w-a1v.w; }
                v.x = pk2h(r0x, r0y); v.y = pk2h(r0z, r0w);
                v.z = pk2h(r1x, r1y); v.w = pk2h(r1z, r1w);
            }
            int mi = mr >> 4, r = mr & 15;
            int cd = (mi*4 + q)*16 + (r ^ (q*2));
            *(uint4*)&lds[cd*8] = v;
        }
        #pragma unroll
        for (int i = 0; i < 2; ++i) {
            int c = tid + i*256;
            int nr = c >> 2, q = c & 3;
            uint4 v = *(const uint4*)&BT[(size_t)(n0 + nr)*Kpad + k0 + q*8];
            int ni = nr >> 4, r = nr & 15;
            int cd = 512 + (ni*4 + q)*16 + (r ^ (q*2));
            *(uint4*)&lds[cd*8] = v;
        }
        __syncthreads();
        f16x8 afr[4], bfr[4];
        #pragma unroll
        for (int mi = 0; mi < 4; ++mi) {
            int mi8 = wm*4 + mi;
            int cd = (mi8*4 + quad)*16 + (lr ^ (quad*2));
            afr[mi] = *(const f16x8*)&lds[cd*8];
        }
        #pragma unroll
        for (int ni = 0; ni < 4; ++ni) {
            int ni8 = wn*4 + ni;
            int cd = 512 + (ni8*4 + quad)*16 + (lr ^ (quad*2));
            bfr[ni] = *(const f16x8*)&lds[cd*8];
        }
        #pragma unroll
        for (int mi = 0; mi < 4; ++mi)
            #pragma unroll
            for (int ni = 0; ni < 4; ++ni)
                acc[mi][ni] = __builtin_amdgcn_mfma_f32_16x16x32_f16(afr[mi], bfr[ni], acc[mi][ni], 0, 0, 0);
        __syncthreads();
    }
    #pragma unroll
    for (int mi = 0; mi < 4; ++mi) {
        int mbase = m0 + (wm*4 + mi)*16 + quad*4;
        #pragma unroll
        for (int ni = 0; ni < 4; ++ni) {
            int n = n0 + (wn*4 + ni)*16 + lr;
            if (OMODE == 0) {
                if (n < N) {
                    float bv = bias ? bias[n] : 0.f;
                    float* C = (float*)Cv;
                    #pragma unroll
                    for (int r2 = 0; r2 < 4; ++r2) {
                        float v = acc[mi][ni][r2] + bv;
                        if (ACT) v = fmaxf(v, 0.f);
                        C[(size_t)(mbase + r2)*ldc + n] = v;
                    }
                }
            } else if (OMODE == 1) {
                if (n < N) {
                    float bv = bias ? bias[n] : 0.f;
                    int t = mbase >> 6, b0 = mbase & 63;
                    uint2 o;
                    o.x = pk2h(acc[mi][ni][0] + bv, acc[mi][ni][1] + bv);
                    o.y = pk2h(acc[mi][ni][2] + bv, acc[mi][ni][3] + bv);
                    *(uint2*)&((ushort_t*)Cv)[((size_t)t*NH4 + n)*NB + b0] = o;
                }
            } else {
                if (n < ldc) {
                    float bv = (bias && n < N) ? bias[n] : 0.f;
                    ushort_t* C = (ushort_t*)Cv;
                    #pragma unroll
                    for (int r2 = 0; r2 < 4; ++r2) {
                        float v = acc[mi][ni][r2] + bv;
                        if (ACT) v = fmaxf(v, 0.f);
                        C[(size_t)(mbase + r2)*ldc + n] = (n < N) ? f2h(v) : (ushort_t)0;
                    }
                }
            }
        }
    }
}

// ---------------- generic tiled SIMT GEMM (attention) ----------------
template<int APERM, int OMODE, int ACT>
__global__ void k_gemm_nn(const float* __restrict__ A, const float* __restrict__ Bm,
                          const float* __restrict__ bias, void* __restrict__ Cv,
                          int M, int N, int K,
                          long long strideA, long long strideB, long long strideC)
{
    int bz = blockIdx.z;
    const float* Ab = A + (size_t)bz*strideA;
    const float* Bb = Bm + (size_t)bz*strideB;
    __shared__ float As[16][64];
    __shared__ float Bs[16][68];
    int n0 = blockIdx.x*64, m0 = blockIdx.y*64;
    int tid = threadIdx.x;
    int tm = tid/16, tn = tid - tm*16;
    float acc[4][4] = {};
    for (int k0 = 0; k0 < K; k0 += 16) {
        {
            int row = tid>>2, kq = tid&3;
            int m = m0 + row;
            int arow;
            if (APERM) { int tq = m>>6, bb = m&63; arow = bb*NS + tq; } else arow = m;
            const float* src = Ab + (size_t)arow*K + k0 + kq*4;
            float4 v;
            if (k0 + 16 <= K) v = *(const float4*)src;
            else {
                v.x = (k0+kq*4+0 < K)? src[0] : 0.f;
                v.y = (k0+kq*4+1 < K)? src[1] : 0.f;
                v.z = (k0+kq*4+2 < K)? src[2] : 0.f;
                v.w = (k0+kq*4+3 < K)? src[3] : 0.f;
            }
            As[kq*4+0][row]=v.x; As[kq*4+1][row]=v.y; As[kq*4+2][row]=v.z; As[kq*4+3][row]=v.w;
        }
        {
            int kk = tid>>4, nq = tid&15;
            int n = n0 + nq*4; int kg = k0 + kk;
            float4 v = {0,0,0,0};
            if (kg < K) {
                const float* src = Bb + (size_t)kg*N + n;
                if (n + 4 <= N) v = *(const float4*)src;
                else { if(n+0<N)v.x=src[0]; if(n+1<N)v.y=src[1]; if(n+2<N)v.z=src[2]; }
            }
            Bs[kk][nq*4+0]=v.x; Bs[kk][nq*4+1]=v.y; Bs[kk][nq*4+2]=v.z; Bs[kk][nq*4+3]=v.w;
        }
        __syncthreads();
        #pragma unroll
        for (int kk = 0; kk < 16; ++kk) {
            float4 a  = *(const float4*)&As[kk][tm*4];
            float4 bq = *(const float4*)&Bs[kk][tn*4];
            acc[0][0]+=a.x*bq.x; acc[0][1]+=a.x*bq.y; acc[0][2]+=a.x*bq.z; acc[0][3]+=a.x*bq.w;
            acc[1][0]+=a.y*bq.x; acc[1][1]+=a.y*bq.y; acc[1][2]+=a.y*bq.z; acc[1][3]+=a.y*bq.w;
            acc[2][0]+=a.z*bq.x; acc[2][1]+=a.z*bq.y; acc[2][2]+=a.z*bq.z; acc[2][3]+=a.z*bq.w;
            acc[3][0]+=a.w*bq.x; acc[3][1]+=a.w*bq.y; acc[3][2]+=a.w*bq.z; acc[3][3]+=a.w*bq.w;
        }
        __syncthreads();
    }
    #pragma unroll
    for (int i = 0; i < 4; ++i) {
        int m = m0 + tm*4 + i;
        #pragma unroll
        for (int j = 0; j < 4; ++j) {
            int n = n0 + tn*4 + j;
            if (n >= N) continue;
            float val = acc[i][j];
            if (bias) val += bias[n];
            if (ACT == 1) val = fmaxf(val, 0.f);
            float* C = (float*)Cv + (size_t)bz*strideC;
            C[(size_t)m*N + n] = val;
        }
    }
}

// ---------------- batched sim = h1 @ h2^T ----------------
__global__ void k_gemm_nt_sim(const float* __restrict__ h1g, const float* __restrict__ h2g,
                              float* __restrict__ sim, float* __restrict__ simT)
{
    int bz = blockIdx.z;
    const float* Ab = h1g + (size_t)bz*NS*(2*NU);
    const float* Bb = h2g + (size_t)bz*NS*(2*NU);
    __shared__ float As[16][64];
    __shared__ float Bs[16][68];
    int n0 = blockIdx.x*64, m0 = blockIdx.y*64;
    int tid = threadIdx.x;
    int tm = tid/16, tn = tid - tm*16;
    float acc[4][4] = {};
    const int K = 2*NU;
    for (int k0 = 0; k0 < K; k0 += 16) {
        int row = tid>>2, kq = tid&3;
        bool full = (k0 + 16 <= K);
        {
            const float* src = Ab + (size_t)(m0+row)*K + k0 + kq*4;
            float4 v = {0,0,0,0};
            if (full) v = *(const float4*)src;
            else { if(k0+kq*4+0<K)v.x=src[0]; if(k0+kq*4+1<K)v.y=src[1];
                   if(k0+kq*4+2<K)v.z=src[2]; if(k0+kq*4+3<K)v.w=src[3]; }
            As[kq*4+0][row]=v.x; As[kq*4+1][row]=v.y; As[kq*4+2][row]=v.z; As[kq*4+3][row]=v.w;
        }
        {
            const float* src = Bb + (size_t)(n0+row)*K + k0 + kq*4;
            float4 v = {0,0,0,0};
            if (full) v = *(const float4*)src;
            else { if(k0+kq*4+0<K)v.x=src[0]; if(k0+kq*4+1<K)v.y=src[1];
                   if(k0+kq*4+2<K)v.z=src[2]; if(k0+kq*4+3<K)v.w=src[3]; }
            Bs[kq*4+0][row]=v.x; Bs[kq*4+1][row]=v.y; Bs[kq*4+2][row]=v.z; Bs[kq*4+3][row]=v.w;
        }
        __syncthreads();
        #pragma unroll
        for (int kk = 0; kk < 16; ++kk) {
            float4 a  = *(const float4*)&As[kk][tm*4];
            float4 bq = *(const float4*)&Bs[kk][tn*4];
            acc[0][0]+=a.x*bq.x; acc[0][1]+=a.x*bq.y; acc[0][2]+=a.x*bq.z; acc[0][3]+=a.x*bq.w;
            acc[1][0]+=a.y*bq.x; acc[1][1]+=a.y*bq.y; acc[1][2]+=a.y*bq.z; acc[1][3]+=a.y*bq.w;
            acc[2][0]+=a.z*bq.x; acc[2][1]+=a.z*bq.y; acc[2][2]+=a.z*bq.z; acc[2][3]+=a.z*bq.w;
            acc[3][0]+=a.w*bq.x; acc[3][1]+=a.w*bq.y; acc[3][2]+=a.w*bq.z; acc[3][3]+=a.w*bq.w;
        }
        __syncthreads();
    }
    #pragma unroll
    for (int i = 0; i < 4; ++i) {
        int m = m0 + tm*4 + i;
        #pragma unroll
        for (int j = 0; j < 4; ++j) {
            int n = n0 + tn*4 + j;
            float val = acc[i][j];
            sim [((size_t)bz*NS + m)*NS + n] = val;
            simT[((size_t)bz*NS + n)*NS + m] = val;
        }
    }
}

// ---------------- row softmax (rows of length NS=128) ----------------
__global__ void k_softmax(const float* __restrict__ in, float* __restrict__ out)
{
    int r = blockIdx.x, tid = threadIdx.x;
    float v = in[(size_t)r*NS + tid];
    float m = v;
    for (int o = 32; o > 0; o >>= 1) m = fmaxf(m, __shfl_down(m, o, 64));
    __shared__ float red[2];
    if ((tid & 63) == 0) red[tid>>6] = m;
    __syncthreads();
    m = fmaxf(red[0], red[1]);
    float e = __expf(v - m);
    float s = e;
    for (int o = 32; o > 0; o >>= 1) s += __shfl_down(s, o, 64);
    __shared__ float red2[2];
    if ((tid & 63) == 0) red2[tid>>6] = s;
    __syncthreads();
    s = red2[0] + red2[1];
    out[(size_t)r*NS + tid] = e / s;
}

// ---------------- persistent bidirectional LSTM scan: weights LDS-resident ---------
// grid (JT=19 j-tiles, 4 scans) = 76 blocks, 256 threads (4 waves).
// Block owns 16 units x ALL 64 batches of one scan; its 40 KB fragment-packed
// weight slice loads into LDS ONCE. h exchanged via global h^T ping-pong
// (fp16 [2][4][64][HXP]); per-scan 19-arrival release/acquire barrier per step
// (128B-padded counters; relaxed poll; single ACQUIRE load for the L2 inv).
// Ping-pong => one barrier/step is sufficient (write->read dependency only).
__global__ __launch_bounds__(256) void k_lstm_scan(
    const ushort_t* __restrict__ pre0, const ushort_t* __restrict__ pre1,
    const ushort_t* __restrict__ pre2, const ushort_t* __restrict__ pre3,
    const ushort_t* __restrict__ wpF, const ushort_t* __restrict__ wpB,
    float* __restrict__ hT1, float* __restrict__ hT2,
    ushort_t* __restrict__ hx, int* __restrict__ bar)
{
    __shared__ __align__(16) ushort_t wl[4*KIT*64*8];   // 40 KB: [g][kit][lane][8]
    int j = blockIdx.x, scan = blockIdx.y;
    int tid = threadIdx.x, w = tid >> 6, lane = tid & 63;
    int quad = lane >> 4, lr = lane & 15;
    const ushort_t* pre = (scan==0)?pre0:(scan==1)?pre1:(scan==2)?pre2:pre3;
    const ushort_t* wp = ((scan & 1) ? wpB : wpF) + (size_t)(j*4)*KIT*64*8;
    float* hT = (scan < 2) ? hT1 : hT2;
    int coff = (scan & 1) ? NU : 0;
    int* mybar = bar + scan*32;          // 128B-padded per-scan counter
    int b = w*16 + lr;                   // this lane's batch
    int u0 = j*16;
    // stage weights once (40 KB, uint4)
    {
        const uint4* s = (const uint4*)wp;
        uint4* d = (uint4*)wl;
        for (int i = tid; i < 4*KIT*64; i += 256) d[i] = s[i];
    }
    __syncthreads();
    float creg[4] = {};
    for (int t = 0; t < NS; ++t) {
        int tt = (scan & 1) ? (NS-1-t) : t;
        const ushort_t* pp = pre + (size_t)tt*NH4*NB;
        f32x4 acc[4] = {};
        if (t > 0) {
            // ---- per-scan barrier #t: publishes h_{t-1} of all 19 blocks ----
            __syncthreads();             // drains this block's h stores (vmcnt 0)
            if (tid == 0) {
                __hip_atomic_fetch_add(mybar, 1, __ATOMIC_RELEASE, __HIP_MEMORY_SCOPE_AGENT);
                while (__hip_atomic_load(mybar, __ATOMIC_RELAXED, __HIP_MEMORY_SCOPE_AGENT) < JT*t)
                    __builtin_amdgcn_s_sleep(1);
                (void)__hip_atomic_load(mybar, __ATOMIC_ACQUIRE, __HIP_MEMORY_SCOPE_AGENT);
            }
            __syncthreads();
            // ---- B-frags: h^T rows for this lane's batch (10 x b128 from L2/L3) ----
            const ushort_t* hrow = hx + ((size_t)(((t-1)&1)*4 + scan)*64 + b)*HXP;
            f16x8 bfr[KIT];
            #pragma unroll
            for (int kit = 0; kit < KIT; ++kit)
                bfr[kit] = *(const f16x8*)&hrow[kit*32 + quad*8];
            // ---- 4 gates x 10 kit MFMA, weights from LDS ----
            #pragma unroll
            for (int g = 0; g < 4; ++g) {
                #pragma unroll
                for (int kit = 0; kit < KIT; ++kit) {
                    f16x8 af = *(const f16x8*)&wl[((g*KIT + kit)*64 + lane)*8];
                    acc[g] = __builtin_amdgcn_mfma_f32_16x16x32_f16(af, bfr[kit], acc[g], 0, 0, 0);
                }
            }
        }
        ushort_t hb[4];
        #pragma unroll
        for (int r = 0; r < 4; ++r) {
            int u = u0 + quad*4 + r;
            if (u < NU) {
                float iv = acc[0][r] + h2f_(pp[(0*NU+u)*NB + b]);
                float gv = acc[1][r] + h2f_(pp[(1*NU+u)*NB + b]);
                float fv = acc[2][r] + h2f_(pp[(2*NU+u)*NB + b]);
                float ov = acc[3][r] + h2f_(pp[(3*NU+u)*NB + b]);
                float c = sigf(fv + 1.0f)*creg[r] + sigf(iv)*tanhf_(gv);
                float h = sigf(ov)*tanhf_(c);
                creg[r] = c;
                hb[r] = f2h(h);
                hT[((size_t)tt*(2*NU) + coff + u)*NB + b] = h;
            } else hb[r] = 0;
        }
        uint2 o;
        o.x = (uint_t)hb[0] | ((uint_t)hb[1] << 16);
        o.y = (uint_t)hb[2] | ((uint_t)hb[3] << 16);
        *(uint2*)&hx[((size_t)((t&1)*4 + scan)*64 + b)*HXP + u0 + quad*4] = o;
    }
}

// ---------------- pool ----------------
__global__ void k_pool(const float* __restrict__ dT, float* __restrict__ v, int voff)
{
    int u = blockIdx.x*4 + (threadIdx.x >> 6);
    int b = threadIdx.x & 63;
    float s = 0.f, m = -1e30f;
    for (int t = 0; t < NS; ++t) {
        float x = dT[((size_t)t*(2*NU) + u)*NB + b];
        s += x; m = fmaxf(m, x);
    }
    v[(size_t)b*NH8 + voff + u]       = s;
    v[(size_t)b*NH8 + voff + 600 + u] = m;
}

// ---------------- final MLP ----------------
__global__ void k_final(const float* __restrict__ v, const float* __restrict__ W1,
                        const float* __restrict__ b1, const float* __restrict__ W2,
                        const float* __restrict__ b2, float* __restrict__ out)
{
    __shared__ float vl[NH8];
    __shared__ float yl[ND];
    int b = blockIdx.x, tid = threadIdx.x;
    for (int i = tid; i < NH8; i += 320) vl[i] = v[(size_t)b*NH8 + i];
    __syncthreads();
    if (tid < ND) {
        float acc = b1[tid];
        for (int k = 0; k < NH8; ++k) acc += vl[k]*W1[(size_t)k*ND + tid];
        yl[tid] = tanhf_(acc);
    }
    __syncthreads();
    if (tid < NCLS) {
        float acc = b2[tid];
        for (int u = 0; u < ND; ++u) acc += yl[u]*W2[u*NCLS + tid];
        out[b*NCLS + tid] = acc;
    }
}

extern "C" void kernel_launch(void* const* d_in, const int* in_sizes, int n_in,
                              void* d_out, int out_size, void* d_ws, size_t ws_size,
                              hipStream_t stream)
{
    const int*   x1     = (const int*)d_in[0];
    const int*   x2     = (const int*)d_in[1];
    const int*   char1  = (const int*)d_in[2];
    const int*   char2  = (const int*)d_in[3];
    const int*   temp1  = (const int*)d_in[6];
    const int*   temp2  = (const int*)d_in[7];
    const int*   len1   = (const int*)d_in[8];
    const int*   len2   = (const int*)d_in[9];
    const float* wemb   = (const float*)d_in[10];
    const float* cemb   = (const float*)d_in[11];
    const float* cfilt  = (const float*)d_in[12];
    const float* eWxf   = (const float*)d_in[13];
    const float* eWhf   = (const float*)d_in[14];
    const float* ebf    = (const float*)d_in[15];
    const float* eWxb   = (const float*)d_in[16];
    const float* eWhb   = (const float*)d_in[17];
    const float* ebb    = (const float*)d_in[18];
    const float* decW   = (const float*)d_in[19];
    const float* decb   = (const float*)d_in[20];
    const float* dWxf   = (const float*)d_in[21];
    const float* dWhf   = (const float*)d_in[22];
    const float* dbf    = (const float*)d_in[23];
    const float* dWxb   = (const float*)d_in[24];
    const float* dWhb   = (const float*)d_in[25];
    const float* dbb    = (const float*)d_in[26];
    const float* aW1    = (const float*)d_in[27];
    const float* ab1    = (const float*)d_in[28];
    const float* aW2    = (const float*)d_in[29];
    const float* ab2    = (const float*)d_in[30];
    float* outp = (float*)d_out;

    float* W = (float*)d_ws;
    size_t off = 0;
    auto alloc = [&](size_t n){ float* p = W + off; off += n; return p; };
    float* t1   = alloc((size_t)NB*NS*NDIN);
    float* t2   = alloc((size_t)NB*NS*NDIN);
    float* h1   = alloc((size_t)NB*NS*(2*NU));
    float* h2   = alloc((size_t)NB*NS*(2*NU));
    float* hT1  = alloc((size_t)NS*(2*NU)*NB);
    float* hT2  = alloc((size_t)NS*(2*NU)*NB);
    float* vbuf = alloc((size_t)NB*NH8);
    float* eWTfF = alloc((size_t)1280*416/2);
    float* eWTbF = alloc((size_t)1280*416/2);
    float* dWTfF = alloc((size_t)1280*320/2);
    float* dWTbF = alloc((size_t)1280*320/2);
    float* decWTF= alloc((size_t)384*2400/2);
    float* p1bfF = alloc((size_t)8192*320/2);
    float* p2bfF = alloc((size_t)8192*320/2);
    size_t wpsz = (size_t)JT*4*KIT*64*8;         // ushorts per direction
    float* wpEfF = alloc(wpsz/2);
    float* wpEbF = alloc(wpsz/2);
    float* wpDfF = alloc(wpsz/2);
    float* wpDbF = alloc(wpsz/2);
    float* hxF   = alloc((size_t)2*4*64*HXP/2); // fp16 h^T ping-pong exchange
    float* barF  = alloc(256);                   // 2 phases x 4 scans x 32-int pads
    float* preF  = alloc((size_t)4*NS*NH4*NB/2); // fp16: 4 x (NS*NH4*NB)
    ushort_t* eWTf  = (ushort_t*)eWTfF;
    ushort_t* eWTb  = (ushort_t*)eWTbF;
    ushort_t* dWTf  = (ushort_t*)dWTfF;
    ushort_t* dWTb  = (ushort_t*)dWTbF;
    ushort_t* decWT = (ushort_t*)decWTF;
    ushort_t* p1bf  = (ushort_t*)p1bfF;
    ushort_t* p2bf  = (ushort_t*)p2bfF;
    ushort_t* wpEf  = (ushort_t*)wpEfF;
    ushort_t* wpEb  = (ushort_t*)wpEbF;
    ushort_t* wpDf  = (ushort_t*)wpDfF;
    ushort_t* wpDb  = (ushort_t*)wpDbF;
    ushort_t* hx    = (ushort_t*)hxF;
    int*      bar   = (int*)barF;
    ushort_t* preb[4];
    for (int i = 0; i < 4; ++i) preb[i] = (ushort_t*)preF + (size_t)i*NS*NH4*NB;
    // fp32 aliases inside the (phase-idle) pre region:
    float* sim   = preF;
    float* simT  = preF + 1048576;
    float* P1    = preF + 2097152;
    float* P2    = preF + 3145728;
    float* beta  = preF + (size_t)NS*NH4*NB/2;
    float* alpha = preF + (size_t)2*NS*NH4*NB/2;

    // 1. zero tree buffers + h^T exchange (incl. K-pad cols) + barrier counters
    hipMemsetAsync(t1, 0, (size_t)2*NB*NS*NDIN*sizeof(float), stream);
    hipMemsetAsync(hx, 0, (size_t)2*4*64*HXP*sizeof(ushort_t), stream);
    hipMemsetAsync(bar, 0, 256*sizeof(int), stream);
    k_embed<<<NB*NL, 128, 0, stream>>>(x1, char1, wemb, cemb, cfilt, t1);
    k_embed<<<NB*NL, 128, 0, stream>>>(x2, char2, wemb, cemb, cfilt, t2);
    k_tree<<<dim3(2, NB), 256, 0, stream>>>(temp1, len1, t1);
    k_tree<<<dim3(2, NB), 256, 0, stream>>>(temp2, len2, t2);

    // 2. weight prep: fp16 W^T for MFMA GEMMs + fragment-packed recurrent weights
    k_wtb<<<dim3(13,40), dim3(32,8), 0, stream>>>(eWxf, eWTf, 400, 1200, 416, 1280);
    k_wtb<<<dim3(13,40), dim3(32,8), 0, stream>>>(eWxb, eWTb, 400, 1200, 416, 1280);
    k_wtb<<<dim3(10,40), dim3(32,8), 0, stream>>>(dWxf, dWTf, 300, 1200, 320, 1280);
    k_wtb<<<dim3(10,40), dim3(32,8), 0, stream>>>(dWxb, dWTb, 300, 1200, 320, 1280);
    k_wtb<<<dim3(75,12), dim3(32,8), 0, stream>>>(decW, decWT, 2400, 300, 2400, 384);
    k_wpack<<<JT*4*KIT, 64, 0, stream>>>(eWhf, wpEf);
    k_wpack<<<JT*4*KIT, 64, 0, stream>>>(eWhb, wpEb);
    k_wpack<<<JT*4*KIT, 64, 0, stream>>>(dWhf, wpDf);
    k_wpack<<<JT*4*KIT, 64, 0, stream>>>(dWhb, wpDb);

    // 3. encoder pre-activations (MFMA fp16, fp32 A converted in staging)
    k_gemm_mfma<1,1,1,0><<<dim3(10,64), 256, 0, stream>>>(t1, nullptr, eWTf, ebf, preb[0], 1200, 416, 0, 400);
    k_gemm_mfma<1,1,1,0><<<dim3(10,64), 256, 0, stream>>>(t1, nullptr, eWTb, ebb, preb[1], 1200, 416, 0, 400);
    k_gemm_mfma<1,1,1,0><<<dim3(10,64), 256, 0, stream>>>(t2, nullptr, eWTf, ebf, preb[2], 1200, 416, 0, 400);
    k_gemm_mfma<1,1,1,0><<<dim3(10,64), 256, 0, stream>>>(t2, nullptr, eWTb, ebb, preb[3], 1200, 416, 0, 400);

    // 4. encoder LSTM: 76 persistent blocks, per-scan barriers
    k_lstm_scan<<<dim3(JT, 4), 256, 0, stream>>>(preb[0], preb[1], preb[2], preb[3],
                                                 wpEf, wpEb, hT1, hT2, hx, bar);
    k_transp<<<dim3(2,2400), dim3(32,8), 0, stream>>>(hT1, h1, NS*(2*NU), NB);
    k_transp<<<dim3(2,2400), dim3(32,8), 0, stream>>>(hT2, h2, NS*(2*NU), NB);

    // 5. attention (SIMT fp32)
    k_gemm_nt_sim<<<dim3(2,2,NB), 256, 0, stream>>>(h1, h2, sim, simT);
    k_softmax<<<NB*NS, 128, 0, stream>>>(sim,  P1);
    k_softmax<<<NB*NS, 128, 0, stream>>>(simT, P2);
    k_gemm_nn<0,0,0><<<dim3(10,2,NB), 256, 0, stream>>>(P1, h2, nullptr, beta,  NS, 2*NU, NS,
                                                        (long long)NS*NS, (long long)NS*2*NU, (long long)NS*2*NU);
    k_gemm_nn<0,0,0><<<dim3(10,2,NB), 256, 0, stream>>>(P2, h1, nullptr, alpha, NS, 2*NU, NS,
                                                        (long long)NS*NS, (long long)NS*2*NU, (long long)NS*2*NU);

    // 6. m projection (MFMA, fused [h,a,h*a,h-a] staging, fp16 out [8192][320])
    k_gemm_mfma<0,2,2,1><<<dim3(3,64), 256, 0, stream>>>(h1, beta,  decWT, decb, p1bf, 300, 2400, 320, 600);
    k_gemm_mfma<0,2,2,1><<<dim3(3,64), 256, 0, stream>>>(h2, alpha, decWT, decb, p2bf, 300, 2400, 320, 600);

    // 7. decoder pre-activations (MFMA, fp16 A)
    k_gemm_mfma<1,0,1,0><<<dim3(10,64), 256, 0, stream>>>(p1bf, nullptr, dWTf, dbf, preb[0], 1200, 320, 0, 320);
    k_gemm_mfma<1,0,1,0><<<dim3(10,64), 256, 0, stream>>>(p1bf, nullptr, dWTb, dbb, preb[1], 1200, 320, 0, 320);
    k_gemm_mfma<1,0,1,0><<<dim3(10,64), 256, 0, stream>>>(p2bf, nullptr, dWTf, dbf, preb[2], 1200, 320, 0, 320);
    k_gemm_mfma<1,0,1,0><<<dim3(10,64), 256, 0, stream>>>(p2bf, nullptr, dWTb, dbb, preb[3], 1200, 320, 0, 320);

    // 8. decoder LSTM (separate counter region; hx re-used, t=0 ignores stale h)
    k_lstm_scan<<<dim3(JT, 4), 256, 0, stream>>>(preb[0], preb[1], preb[2], preb[3],
                                                 wpDf, wpDb, hT1, hT2, hx, bar + 128);

    // 9. pool + final MLP
    k_pool<<<150, 256, 0, stream>>>(hT1, vbuf, 0);
    k_pool<<<150, 256, 0, stream>>>(hT2, vbuf, 1200);
    k_final<<<NB, 320, 0, stream>>>(vbuf, aW1, ab1, aW2, ab2, outp);
}